// Round 1
// baseline (99.107 us; speedup 1.0000x reference)
//
#include <hip/hip_runtime.h>
#include <hip/hip_bf16.h>

#define DIM      512
#define EDIM     1024
#define OUTD     512
#define BATCH    4
#define LSEQ     4096
#define MROWS    (BATCH * LSEQ)   // 16384
#define NCHUNK   16
#define CHUNK    (LSEQ / NCHUNK)  // 256

typedef __attribute__((ext_vector_type(8))) __bf16 bf16x8;
typedef __attribute__((ext_vector_type(4))) float  f32x4;

static __device__ __forceinline__ ushort f2b(float f) {
    uint x = __float_as_uint(f);
    x += 0x7fff + ((x >> 16) & 1);           // round-to-nearest-even
    return (ushort)(x >> 16);
}
static __device__ __forceinline__ float b2f(ushort u) {
    return __uint_as_float(((uint)u) << 16);
}
static __device__ __forceinline__ float sigmoidf(float x) {
    return 1.0f / (1.0f + expf(-x));
}

// ---------------------------------------------------------------- prep ----
// betaT[n][k] = beta[k][n]  (bf16),  etaT[o][e] = eta[e][o]  (bf16)
// p[e] = sigmoid(la[e]), q[e] = 1 - sigmoid(la)*sigmoid(ld)
__global__ void prep_kernel(const float* __restrict__ beta,
                            const float* __restrict__ eta,
                            const float* __restrict__ la,
                            const float* __restrict__ ld,
                            ushort* __restrict__ betaT,
                            ushort* __restrict__ etaT,
                            float* __restrict__ p,
                            float* __restrict__ q) {
    int i = blockIdx.x * blockDim.x + threadIdx.x;
    if (i < EDIM * DIM) {           // 524288
        int n = i / DIM, k = i - n * DIM;
        betaT[i] = f2b(beta[(size_t)k * EDIM + n]);
    }
    if (i < OUTD * EDIM) {          // 524288
        int o = i / EDIM, e = i - o * EDIM;
        etaT[i] = f2b(eta[(size_t)e * OUTD + o]);
    }
    if (i < EDIM) {
        float a = sigmoidf(la[i]);
        float d = sigmoidf(ld[i]);
        p[i] = a;
        q[i] = 1.0f - a * d;
    }
}

// ------------------------------------------------------------ emb->bf16 ---
__global__ void cvt_emb_kernel(const float* __restrict__ emb,
                               ushort* __restrict__ a16) {
    int i = blockIdx.x * blockDim.x + threadIdx.x;   // one per 4 floats
    float4 v = ((const float4*)emb)[i];
    ushort4 o;
    o.x = f2b(v.x); o.y = f2b(v.y); o.z = f2b(v.z); o.w = f2b(v.w);
    ((ushort4*)a16)[i] = o;
}

// ---------------------------------------------------------------- GEMM ----
// C[M,N] = A[M,K] * Bt[N,K]^T, bf16 inputs, fp32 accumulate.
// 128x128 tile, BK=64, 4 waves (2x2), each wave 64x64 (4x4 frags of 16x16).
// LDS staged with global_load_lds(16B) with XOR-swizzle (pre-swizzled source).
template <int OUT_BF16>
__global__ __launch_bounds__(256) void gemm_bt(const ushort* __restrict__ A,
                                               const ushort* __restrict__ Bt,
                                               void* __restrict__ Cv,
                                               int M, int N, int K) {
    __shared__ ushort smem[16384];   // 32 KB: A tile [0..8191], B tile [8192..16383]
    const int tid  = threadIdx.x;
    const int lane = tid & 63;
    const int wid  = tid >> 6;
    const int wr   = wid >> 1, wc = wid & 1;
    const int l15  = lane & 15;
    const int l4   = lane >> 4;
    const int rowBase = blockIdx.x * 128;
    const int colBase = blockIdx.y * 128;

    f32x4 acc[4][4] = {};

    const int nkb = K >> 6;
    for (int kb = 0; kb < nkb; ++kb) {
        // ---- stage A and B tiles (each 128 rows x 64 k of bf16 = 16 KB) ----
        #pragma unroll
        for (int r = 0; r < 4; ++r) {
            int c     = r * 256 + tid;          // 16B chunk id, 0..1023
            int row   = c >> 3;                 // 0..127
            int col16 = (c & 7) ^ (row & 7);    // pre-swizzled source column
            const ushort* ga = A  + (size_t)(rowBase + row) * K + kb * 64 + col16 * 8;
            __builtin_amdgcn_global_load_lds(
                (const __attribute__((address_space(1))) void*)ga,
                (__attribute__((address_space(3))) void*)((char*)smem + c * 16),
                16, 0, 0);
            const ushort* gb = Bt + (size_t)(colBase + row) * K + kb * 64 + col16 * 8;
            __builtin_amdgcn_global_load_lds(
                (const __attribute__((address_space(1))) void*)gb,
                (__attribute__((address_space(3))) void*)((char*)smem + 16384 + c * 16),
                16, 0, 0);
        }
        __syncthreads();   // drains vmcnt before LDS reads

        #pragma unroll
        for (int kk = 0; kk < 2; ++kk) {
            bf16x8 af[4], bfr[4];
            #pragma unroll
            for (int m = 0; m < 4; ++m) {
                int row   = wr * 64 + m * 16 + l15;
                int kbyte = kk * 64 + l4 * 16;
                int addr  = row * 128 + (kbyte ^ ((row & 7) << 4));
                af[m] = *(const bf16x8*)((const char*)smem + addr);
            }
            #pragma unroll
            for (int n = 0; n < 4; ++n) {
                int row   = wc * 64 + n * 16 + l15;
                int kbyte = kk * 64 + l4 * 16;
                int addr  = 16384 + row * 128 + (kbyte ^ ((row & 7) << 4));
                bfr[n] = *(const bf16x8*)((const char*)smem + addr);
            }
            #pragma unroll
            for (int m = 0; m < 4; ++m)
                #pragma unroll
                for (int n = 0; n < 4; ++n)
                    acc[m][n] = __builtin_amdgcn_mfma_f32_16x16x32_bf16(
                        af[m], bfr[n], acc[m][n], 0, 0, 0);
        }
        __syncthreads();   // protect LDS before next stage
    }

    // ---- epilogue: D lane l reg r -> row = 4*(l>>4)+r, col = l&15 ----
    #pragma unroll
    for (int m = 0; m < 4; ++m)
        #pragma unroll
        for (int n = 0; n < 4; ++n)
            #pragma unroll
            for (int r = 0; r < 4; ++r) {
                int row = rowBase + wr * 64 + m * 16 + l4 * 4 + r;
                int col = colBase + wc * 64 + n * 16 + l15;
                if (OUT_BF16)
                    ((ushort*)Cv)[(size_t)row * N + col] = f2b(acc[m][n][r]);
                else
                    ((float*)Cv)[(size_t)row * N + col] = acc[m][n][r];
            }
}

// ---------------------------------------------------------------- scan ----
// Suffix EMA per (b,e):  out[l] = p * sum_{m>=l} q^(m-l) u[m]
// Phase 1: per-chunk aggregates  agg[b,c,e] = sum_j q^j u[c*256+j]
__global__ void scan_agg_kernel(const ushort* __restrict__ u,
                                const float* __restrict__ qv,
                                float* __restrict__ agg) {
    int t = blockIdx.x * blockDim.x + threadIdx.x;   // 65536
    int e = t & (EDIM - 1);
    int g = t >> 10;
    int b = g >> 4;
    int c = g & 15;
    float qe = qv[e];
    const ushort* up = u + (size_t)(b * LSEQ + c * CHUNK) * EDIM + e;
    float acc = 0.0f, w = 1.0f;
    #pragma unroll 8
    for (int j = 0; j < CHUNK; ++j) {
        acc += w * b2f(up[(size_t)j * EDIM]);
        w *= qe;
    }
    agg[t] = acc;   // layout [(b*16+c)*1024 + e]
}

// Phase 2: in-place apply with cross-chunk carry
__global__ void scan_apply_kernel(ushort* __restrict__ u,
                                  const float* __restrict__ pv,
                                  const float* __restrict__ qv,
                                  const float* __restrict__ agg) {
    int t = blockIdx.x * blockDim.x + threadIdx.x;
    int e = t & (EDIM - 1);
    int g = t >> 10;
    int b = g >> 4;
    int c = g & 15;
    float qe = qv[e], pe = pv[e];
    float qL = qe;                       // q^256 by 8 squarings
    #pragma unroll
    for (int s = 0; s < 8; ++s) qL *= qL;
    // carry = sum_{c'=c+1}^{15} qL^(c'-c-1) * agg[b,c',e]
    float carry = 0.0f, w = 1.0f;
    for (int cp = c + 1; cp < NCHUNK; ++cp) {
        carry += w * agg[((b * NCHUNK + cp) << 10) + e];
        w *= qL;
    }
    ushort* up = u + (size_t)(b * LSEQ + c * CHUNK) * EDIM + e;
    float S = carry;
    #pragma unroll 8
    for (int j = CHUNK - 1; j >= 0; --j) {
        S = b2f(up[(size_t)j * EDIM]) + qe * S;
        up[(size_t)j * EDIM] = f2b(pe * S);
    }
}

// -------------------------------------------------------------- launch ----
extern "C" void kernel_launch(void* const* d_in, const int* in_sizes, int n_in,
                              void* d_out, int out_size, void* d_ws, size_t ws_size,
                              hipStream_t stream) {
    const float* emb  = (const float*)d_in[0];
    const float* la   = (const float*)d_in[1];
    const float* ld   = (const float*)d_in[2];
    const float* beta = (const float*)d_in[3];
    const float* eta  = (const float*)d_in[4];

    char* ws = (char*)d_ws;
    ushort* a16   = (ushort*)(ws);                    // 16 MB  emb bf16
    ushort* betaT = (ushort*)(ws + 16777216);         // 1 MB
    ushort* etaT  = (ushort*)(ws + 17825792);         // 1 MB
    ushort* u     = (ushort*)(ws + 18874368);         // 32 MB  u / out (in-place)
    float*  p     = (float*) (ws + 52428800);         // 4 KB
    float*  q     = (float*) (ws + 52432896);         // 4 KB
    float*  agg   = (float*) (ws + 52436992);         // 256 KB

    prep_kernel<<<dim3(2048), dim3(256), 0, stream>>>(beta, eta, la, ld,
                                                      betaT, etaT, p, q);
    cvt_emb_kernel<<<dim3(8192), dim3(256), 0, stream>>>(emb, a16);

    // u[16384,1024] = emb_bf16[16384,512] @ betaT[1024,512]^T
    gemm_bt<1><<<dim3(MROWS / 128, EDIM / 128), dim3(256), 0, stream>>>(
        a16, betaT, (void*)u, MROWS, EDIM, DIM);

    scan_agg_kernel<<<dim3(256), dim3(256), 0, stream>>>(u, q, agg);
    scan_apply_kernel<<<dim3(256), dim3(256), 0, stream>>>(u, p, q, agg);

    // y[16384,512] = out_bf16[16384,1024] @ etaT[512,1024]^T
    gemm_bt<0><<<dim3(MROWS / 128, OUTD / 128), dim3(256), 0, stream>>>(
        u, etaT, d_out, MROWS, OUTD, EDIM);
}

// Round 2
// 87.280 us; speedup vs baseline: 1.1355x; 1.1355x over previous
//
#include <hip/hip_runtime.h>
#include <hip/hip_bf16.h>

#define DIM      512
#define EDIM     1024
#define OUTD     512
#define BATCH    4
#define LSEQ     4096
#define MROWS    (BATCH * LSEQ)   // 16384
#define NCHUNK   64
#define CHUNK    (LSEQ / NCHUNK)  // 64

typedef __attribute__((ext_vector_type(8))) __bf16 bf16x8;
typedef __attribute__((ext_vector_type(4))) float  f32x4;

static __device__ __forceinline__ ushort f2b(float f) {
    uint x = __float_as_uint(f);
    x += 0x7fff + ((x >> 16) & 1);           // round-to-nearest-even
    return (ushort)(x >> 16);
}
static __device__ __forceinline__ float b2f(ushort u) {
    return __uint_as_float(((uint)u) << 16);
}
static __device__ __forceinline__ float sigmoidf(float x) {
    return 1.0f / (1.0f + expf(-x));
}

// ------------------------------------------------- prep + emb->bf16 -------
// blocks [0,8192): convert emb fp32 -> bf16 (float4 vectorized)
// blocks [8192,10240): transpose beta/eta to [N,K] bf16; p,q from logits
__global__ void prep_cvt_kernel(const float* __restrict__ emb,
                                ushort* __restrict__ a16,
                                const float* __restrict__ beta,
                                const float* __restrict__ eta,
                                const float* __restrict__ la,
                                const float* __restrict__ ld,
                                ushort* __restrict__ betaT,
                                ushort* __restrict__ etaT,
                                float* __restrict__ p,
                                float* __restrict__ q) {
    int blk = blockIdx.x;
    if (blk < 8192) {
        int i = blk * 256 + threadIdx.x;     // one per 4 floats
        float4 v = ((const float4*)emb)[i];
        ushort4 o;
        o.x = f2b(v.x); o.y = f2b(v.y); o.z = f2b(v.z); o.w = f2b(v.w);
        ((ushort4*)a16)[i] = o;
    } else {
        int i = (blk - 8192) * 256 + threadIdx.x;
        if (i < EDIM * DIM) {                // 524288
            int n = i / DIM, k = i - n * DIM;
            betaT[i] = f2b(beta[(size_t)k * EDIM + n]);
        }
        if (i < OUTD * EDIM) {               // 524288
            int o = i / EDIM, e = i - o * EDIM;
            etaT[i] = f2b(eta[(size_t)e * OUTD + o]);
        }
        if (i < EDIM) {
            float a = sigmoidf(la[i]);
            float d = sigmoidf(ld[i]);
            p[i] = a;
            q[i] = 1.0f - a * d;
        }
    }
}

// ---------------------------------------------------------------- GEMM ----
// C[M,N] = A[M,K] * Bt[N,K]^T, bf16 in, fp32 acc. 128x128 tile, BK=64,
// 4 waves (2x2), each wave 64x64 (4x4 frags of 16x16x32 MFMA).
// Col-fastest flat order + XCD-chunked swizzle: A panel streamed once,
// B (1 MB) stays L2-resident.
// DO_AGG: also emit per-chunk EMA aggregates (each wave's 64 rows = 1 chunk):
//   agg[b, chunk, e] = sum_{j=0..63} q_e^j * u[chunk*64+j, e]
template <int OUT_BF16, int DO_AGG>
__global__ __launch_bounds__(256) void gemm_bt(const ushort* __restrict__ A,
                                               const ushort* __restrict__ Bt,
                                               void* __restrict__ Cv,
                                               const float* __restrict__ qv,
                                               float* __restrict__ aggp,
                                               int M, int N, int K,
                                               int ncolShift) {
    __shared__ ushort smem[16384];   // 32 KB: A tile bytes [0,16384), B [16384,32768)
    const int tid  = threadIdx.x;
    const int lane = tid & 63;
    const int wid  = tid >> 6;
    const int wr   = wid >> 1, wc = wid & 1;
    const int l15  = lane & 15;
    const int l4   = lane >> 4;

    // XCD-chunked swizzle (nwg % 8 == 0): each XCD gets contiguous flat range
    const int nwg   = gridDim.x;
    const int chunkw = nwg >> 3;
    const int flat  = (blockIdx.x & 7) * chunkw + (blockIdx.x >> 3);
    const int rowBase = (flat >> ncolShift) << 7;
    const int colBase = (flat & ((1 << ncolShift) - 1)) << 7;

    f32x4 acc[4][4] = {};

    const int nkb = K >> 6;
    for (int kb = 0; kb < nkb; ++kb) {
        #pragma unroll
        for (int r = 0; r < 4; ++r) {
            int c     = r * 256 + tid;          // 16B chunk id, 0..1023
            int row   = c >> 3;                 // 0..127
            int col16 = (c & 7) ^ (row & 7);    // pre-swizzled source column
            const ushort* ga = A  + (size_t)(rowBase + row) * K + kb * 64 + col16 * 8;
            __builtin_amdgcn_global_load_lds(
                (const __attribute__((address_space(1))) void*)ga,
                (__attribute__((address_space(3))) void*)((char*)smem + c * 16),
                16, 0, 0);
            const ushort* gb = Bt + (size_t)(colBase + row) * K + kb * 64 + col16 * 8;
            __builtin_amdgcn_global_load_lds(
                (const __attribute__((address_space(1))) void*)gb,
                (__attribute__((address_space(3))) void*)((char*)smem + 16384 + c * 16),
                16, 0, 0);
        }
        __syncthreads();

        #pragma unroll
        for (int kk = 0; kk < 2; ++kk) {
            bf16x8 af[4], bfr[4];
            #pragma unroll
            for (int m = 0; m < 4; ++m) {
                int row   = wr * 64 + m * 16 + l15;
                int kbyte = kk * 64 + l4 * 16;
                int addr  = row * 128 + (kbyte ^ ((row & 7) << 4));
                af[m] = *(const bf16x8*)((const char*)smem + addr);
            }
            #pragma unroll
            for (int n = 0; n < 4; ++n) {
                int row   = wc * 64 + n * 16 + l15;
                int kbyte = kk * 64 + l4 * 16;
                int addr  = 16384 + row * 128 + (kbyte ^ ((row & 7) << 4));
                bfr[n] = *(const bf16x8*)((const char*)smem + addr);
            }
            #pragma unroll
            for (int m = 0; m < 4; ++m)
                #pragma unroll
                for (int n = 0; n < 4; ++n)
                    acc[m][n] = __builtin_amdgcn_mfma_f32_16x16x32_bf16(
                        af[m], bfr[n], acc[m][n], 0, 0, 0);
        }
        __syncthreads();
    }

    // ---- C store: D lane l reg r -> row = 4*(l>>4)+r, col = l&15 ----
    #pragma unroll
    for (int m = 0; m < 4; ++m)
        #pragma unroll
        for (int n = 0; n < 4; ++n)
            #pragma unroll
            for (int r = 0; r < 4; ++r) {
                int row = rowBase + wr * 64 + m * 16 + l4 * 4 + r;
                int col = colBase + wc * 64 + n * 16 + l15;
                if (OUT_BF16)
                    ((ushort*)Cv)[(size_t)row * N + col] = f2b(acc[m][n][r]);
                else
                    ((float*)Cv)[(size_t)row * N + col] = acc[m][n][r];
            }

    // ---- fused per-chunk EMA aggregate (wave's 64 rows = one chunk) ----
    if (DO_AGG) {
        const int bidx     = rowBase >> 12;                    // batch
        const int chunkIdx = ((rowBase & 4095) >> 6) + wr;     // 64-row chunk
        #pragma unroll
        for (int n = 0; n < 4; ++n) {
            int col = colBase + wc * 64 + n * 16 + l15;
            float qe = qv[col];
            float q2 = qe * qe, q4 = q2 * q2, q8 = q4 * q4, q16 = q8 * q8;
            // in-lane rows: m*16 + l4*4 + r  (r Horner, then m Horner in q16)
            float P = 0.0f;
            #pragma unroll
            for (int m = 3; m >= 0; --m) {
                f32x4 a = acc[m][n];
                float pm = ((a[3] * qe + a[2]) * qe + a[1]) * qe + a[0];
                P = P * q16 + pm;
            }
            float ql4 = (l4 & 1 ? q4 : 1.0f) * (l4 & 2 ? q8 : 1.0f);
            P *= ql4;                                   // weight q^(4*l4)
            P += __shfl_xor(P, 16, 64);
            P += __shfl_xor(P, 32, 64);
            if (l4 == 0)
                aggp[(((bidx << 6) | chunkIdx) << 10) + col] = P;
        }
    }
}

// ---------------------------------------------------------------- scan ----
// In-place suffix EMA apply with cross-chunk carry from agg.
// out[l] = p * sum_{m>=l} q^(m-l) u[m];  chunk = 64 rows; 2 channels/thread.
__global__ void scan_apply_kernel(ushort* __restrict__ u,
                                  const float* __restrict__ pv,
                                  const float* __restrict__ qv,
                                  const float* __restrict__ agg) {
    int t = blockIdx.x * blockDim.x + threadIdx.x;   // 131072
    int e0 = (t & 511) * 2;
    int c  = (t >> 9) & 63;
    int b  = t >> 15;
    float2 qe2 = *(const float2*)(qv + e0);
    float2 pe2 = *(const float2*)(pv + e0);
    float qe[2] = {qe2.x, qe2.y};
    float pe[2] = {pe2.x, pe2.y};
    float qL[2], S[2], w[2];
    #pragma unroll
    for (int k = 0; k < 2; ++k) {
        float x = qe[k];
        #pragma unroll
        for (int s = 0; s < 6; ++s) x *= x;    // q^64
        qL[k] = x; S[k] = 0.0f; w[k] = 1.0f;
    }
    // carry = sum_{c'>c} qL^(c'-c-1) * agg[b,c',e]
    for (int cp = c + 1; cp < NCHUNK; ++cp) {
        float2 a = *(const float2*)(agg + (((b << 6) | cp) << 10) + e0);
        S[0] += w[0] * a.x;  w[0] *= qL[0];
        S[1] += w[1] * a.y;  w[1] *= qL[1];
    }
    ushort* up = u + ((size_t)(b * LSEQ + c * CHUNK) << 10) + e0;
    #pragma unroll 4
    for (int j = CHUNK - 1; j >= 0; --j) {
        ushort2 uv = *(ushort2*)(up + (size_t)j * EDIM);
        S[0] = b2f(uv.x) + qe[0] * S[0];
        S[1] = b2f(uv.y) + qe[1] * S[1];
        ushort2 ov;
        ov.x = f2b(pe[0] * S[0]);
        ov.y = f2b(pe[1] * S[1]);
        *(ushort2*)(up + (size_t)j * EDIM) = ov;
    }
}

// -------------------------------------------------------------- launch ----
extern "C" void kernel_launch(void* const* d_in, const int* in_sizes, int n_in,
                              void* d_out, int out_size, void* d_ws, size_t ws_size,
                              hipStream_t stream) {
    const float* emb  = (const float*)d_in[0];
    const float* la   = (const float*)d_in[1];
    const float* ld   = (const float*)d_in[2];
    const float* beta = (const float*)d_in[3];
    const float* eta  = (const float*)d_in[4];

    char* ws = (char*)d_ws;
    ushort* a16   = (ushort*)(ws);                    // 16 MB  emb bf16
    ushort* betaT = (ushort*)(ws + 16777216);         // 1 MB
    ushort* etaT  = (ushort*)(ws + 17825792);         // 1 MB
    ushort* u     = (ushort*)(ws + 18874368);         // 32 MB  u / out (in-place)
    float*  p     = (float*) (ws + 52428800);         // 4 KB
    float*  q     = (float*) (ws + 52432896);         // 4 KB
    float*  agg   = (float*) (ws + 52436992);         // 1 MB [4][64][1024]

    prep_cvt_kernel<<<dim3(10240), dim3(256), 0, stream>>>(
        emb, a16, beta, eta, la, ld, betaT, etaT, p, q);

    // u[16384,1024] = emb_bf16[16384,512] @ betaT[1024,512]^T  (+ chunk agg)
    gemm_bt<1, 1><<<dim3((MROWS / 128) * (EDIM / 128)), dim3(256), 0, stream>>>(
        a16, betaT, (void*)u, q, agg, MROWS, EDIM, DIM, 3);

    scan_apply_kernel<<<dim3(512), dim3(256), 0, stream>>>(u, p, q, agg);

    // y[16384,512] = out_bf16[16384,1024] @ etaT[512,1024]^T
    gemm_bt<0, 0><<<dim3((MROWS / 128) * (OUTD / 128)), dim3(256), 0, stream>>>(
        u, etaT, d_out, nullptr, nullptr, MROWS, OUTD, EDIM, 2);
}

// Round 3
// 83.740 us; speedup vs baseline: 1.1835x; 1.0423x over previous
//
#include <hip/hip_runtime.h>
#include <hip/hip_bf16.h>

#define DIM      512
#define EDIM     1024
#define OUTD     512
#define BATCH    4
#define LSEQ     4096
#define MROWS    (BATCH * LSEQ)   // 16384
#define NCHUNK   64
#define CHUNK    (LSEQ / NCHUNK)  // 64

typedef __attribute__((ext_vector_type(8))) __bf16 bf16x8;
typedef __attribute__((ext_vector_type(4))) float  f32x4;

static __device__ __forceinline__ ushort f2b(float f) {
    uint x = __float_as_uint(f);
    x += 0x7fff + ((x >> 16) & 1);           // round-to-nearest-even
    return (ushort)(x >> 16);
}
static __device__ __forceinline__ float b2f(ushort u) {
    return __uint_as_float(((uint)u) << 16);
}
static __device__ __forceinline__ float sigmoidf(float x) {
    return 1.0f / (1.0f + expf(-x));
}

// ------------------------------------------------- prep + emb->bf16 -------
__global__ void prep_cvt_kernel(const float* __restrict__ emb,
                                ushort* __restrict__ a16,
                                const float* __restrict__ beta,
                                const float* __restrict__ eta,
                                const float* __restrict__ la,
                                const float* __restrict__ ld,
                                ushort* __restrict__ betaT,
                                ushort* __restrict__ etaT,
                                float* __restrict__ p,
                                float* __restrict__ q) {
    int blk = blockIdx.x;
    if (blk < 8192) {
        int i = blk * 256 + threadIdx.x;     // one per 4 floats
        float4 v = ((const float4*)emb)[i];
        ushort4 o;
        o.x = f2b(v.x); o.y = f2b(v.y); o.z = f2b(v.z); o.w = f2b(v.w);
        ((ushort4*)a16)[i] = o;
    } else {
        int i = (blk - 8192) * 256 + threadIdx.x;
        if (i < EDIM * DIM) {
            int n = i / DIM, k = i - n * DIM;
            betaT[i] = f2b(beta[(size_t)k * EDIM + n]);
        }
        if (i < OUTD * EDIM) {
            int o = i / EDIM, e = i - o * EDIM;
            etaT[i] = f2b(eta[(size_t)e * OUTD + o]);
        }
        if (i < EDIM) {
            float a = sigmoidf(la[i]);
            float d = sigmoidf(ld[i]);
            p[i] = a;
            q[i] = 1.0f - a * d;
        }
    }
}

// ------------------------------------------- GEMM 256x256 8-phase ---------
// C[M,N] = A[M,K]*Bt[N,K]^T. BM=BN=256, BK=64, 8 waves (2Mx4N), per-wave
// 128x64. 2 K-tile LDS buffers (128 KB dynamic). Stage t+1 at top of tile t
// (8 global_load_lds), drain once per tile just before last barrier.
// 4 phases/tile: {ds_reads; barrier; setprio1; 16 MFMA; setprio0; barrier}.
#define MFMA_BF16 __builtin_amdgcn_mfma_f32_16x16x32_bf16
template <int KDIM, int NSHIFT, int OUT_BF16, int DO_AGG>
__global__ __launch_bounds__(512, 2) void gemm256(const ushort* __restrict__ A,
                                                  const ushort* __restrict__ Bt,
                                                  void* __restrict__ Cv,
                                                  const float* __restrict__ qv,
                                                  float* __restrict__ aggp,
                                                  int N) {
    extern __shared__ __align__(16) char smem[];   // 131072 bytes
    const int tid  = threadIdx.x;
    const int lane = tid & 63;
    const int wid  = tid >> 6;       // 0..7
    const int wr   = wid >> 2;       // 0..1  (M half)
    const int wc   = wid & 3;        // 0..3  (N quarter)
    const int l15  = lane & 15;
    const int l4   = lane >> 4;

    const int nwg  = gridDim.x;      // multiple of 8
    const int flat = ((int)blockIdx.x & 7) * (nwg >> 3) + ((int)blockIdx.x >> 3);
    const int rowBase = (flat >> NSHIFT) << 8;
    const int colBase = (flat & ((1 << NSHIFT) - 1)) << 8;

    // staging: chunk c = i*512 + tid (i=0..3 per operand), 16B each
    const int row0  = tid >> 3;                 // 0..63, +64 per i
    const int col16 = (tid & 7) ^ (row0 & 7);   // pre-swizzled source column
    const ushort* gA0 = A  + (size_t)(rowBase + row0) * KDIM + col16 * 8;
    const ushort* gB0 = Bt + (size_t)(colBase + row0) * KDIM + col16 * 8;
    const int ldsOff = tid * 16;                // + i*8192 (+32768 for B)

    // ds_read bases: byte = row*128 + (kbyte ^ ((row&7)<<4)), row&7 == l15&7
    const int sw   = (l15 & 7) << 4;
    const int aRow = (wr * 128 + l15) * 128;
    const int bRow = 32768 + (wc * 64 + l15) * 128;
    const int a0 = aRow + ((l4 * 16) ^ sw);
    const int a1 = aRow + ((64 + l4 * 16) ^ sw);
    const int b0 = bRow + ((l4 * 16) ^ sw);
    const int b1 = bRow + ((64 + l4 * 16) ^ sw);

    f32x4 acc[8][4] = {};
    bf16x8 af[4][2], bfr[4][2];

    const int NT = KDIM >> 6;

    auto STAGE = [&](int t) {
        const int boff = (t & 1) << 16;
        const size_t koff = (size_t)t * 64;
        #pragma unroll
        for (int i = 0; i < 4; ++i)
            __builtin_amdgcn_global_load_lds(
                (const __attribute__((address_space(1))) void*)(gA0 + (size_t)i * 64 * KDIM + koff),
                (__attribute__((address_space(3))) void*)(smem + boff + i * 8192 + ldsOff),
                16, 0, 0);
        #pragma unroll
        for (int i = 0; i < 4; ++i)
            __builtin_amdgcn_global_load_lds(
                (const __attribute__((address_space(1))) void*)(gB0 + (size_t)i * 64 * KDIM + koff),
                (__attribute__((address_space(3))) void*)(smem + boff + 32768 + i * 8192 + ldsOff),
                16, 0, 0);
    };

    STAGE(0);
    asm volatile("s_waitcnt vmcnt(0)" ::: "memory");
    __builtin_amdgcn_s_barrier();

    for (int t = 0; t < NT; ++t) {
        const char* sm = smem + ((t & 1) << 16);
        if (t + 1 < NT) STAGE(t + 1);          // prefetch next tile (other buf)
        // ---- phase 1: read A[m0-3], B[n0-1]; MFMA m0-3 x n0-1 ----
        #pragma unroll
        for (int m = 0; m < 4; ++m) {
            af[m][0] = *(const bf16x8*)(sm + a0 + m * 2048);
            af[m][1] = *(const bf16x8*)(sm + a1 + m * 2048);
        }
        #pragma unroll
        for (int n = 0; n < 2; ++n) {
            bfr[n][0] = *(const bf16x8*)(sm + b0 + n * 2048);
            bfr[n][1] = *(const bf16x8*)(sm + b1 + n * 2048);
        }
        __builtin_amdgcn_s_barrier();
        __builtin_amdgcn_s_setprio(1);
        #pragma unroll
        for (int m = 0; m < 4; ++m)
            #pragma unroll
            for (int n = 0; n < 2; ++n) {
                acc[m][n] = MFMA_BF16(af[m][0], bfr[n][0], acc[m][n], 0, 0, 0);
                acc[m][n] = MFMA_BF16(af[m][1], bfr[n][1], acc[m][n], 0, 0, 0);
            }
        __builtin_amdgcn_s_setprio(0);
        __builtin_amdgcn_s_barrier();
        // ---- phase 2: read B[n2-3]; MFMA m0-3 x n2-3 ----
        #pragma unroll
        for (int n = 2; n < 4; ++n) {
            bfr[n][0] = *(const bf16x8*)(sm + b0 + n * 2048);
            bfr[n][1] = *(const bf16x8*)(sm + b1 + n * 2048);
        }
        __builtin_amdgcn_s_barrier();
        __builtin_amdgcn_s_setprio(1);
        #pragma unroll
        for (int m = 0; m < 4; ++m)
            #pragma unroll
            for (int n = 2; n < 4; ++n) {
                acc[m][n] = MFMA_BF16(af[m][0], bfr[n][0], acc[m][n], 0, 0, 0);
                acc[m][n] = MFMA_BF16(af[m][1], bfr[n][1], acc[m][n], 0, 0, 0);
            }
        __builtin_amdgcn_s_setprio(0);
        __builtin_amdgcn_s_barrier();
        // ---- phase 3: read A[m4-7] (reuse regs); MFMA m4-7 x n0-1 ----
        #pragma unroll
        for (int m = 0; m < 4; ++m) {
            af[m][0] = *(const bf16x8*)(sm + a0 + (m + 4) * 2048);
            af[m][1] = *(const bf16x8*)(sm + a1 + (m + 4) * 2048);
        }
        __builtin_amdgcn_s_barrier();
        __builtin_amdgcn_s_setprio(1);
        #pragma unroll
        for (int m = 0; m < 4; ++m)
            #pragma unroll
            for (int n = 0; n < 2; ++n) {
                acc[m + 4][n] = MFMA_BF16(af[m][0], bfr[n][0], acc[m + 4][n], 0, 0, 0);
                acc[m + 4][n] = MFMA_BF16(af[m][1], bfr[n][1], acc[m + 4][n], 0, 0, 0);
            }
        __builtin_amdgcn_s_setprio(0);
        __builtin_amdgcn_s_barrier();
        // ---- phase 4: MFMA m4-7 x n2-3; drain prefetch; barrier ----
        __builtin_amdgcn_s_setprio(1);
        #pragma unroll
        for (int m = 0; m < 4; ++m)
            #pragma unroll
            for (int n = 2; n < 4; ++n) {
                acc[m + 4][n] = MFMA_BF16(af[m][0], bfr[n][0], acc[m + 4][n], 0, 0, 0);
                acc[m + 4][n] = MFMA_BF16(af[m][1], bfr[n][1], acc[m + 4][n], 0, 0, 0);
            }
        __builtin_amdgcn_s_setprio(0);
        asm volatile("s_waitcnt vmcnt(0)" ::: "memory");
        __builtin_amdgcn_s_barrier();
    }

    // ---- C store: lane l reg r -> row = m*16 + 4*l4 + r, col = n*16 + l15
    #pragma unroll
    for (int m = 0; m < 8; ++m)
        #pragma unroll
        for (int n = 0; n < 4; ++n)
            #pragma unroll
            for (int r = 0; r < 4; ++r) {
                int row = rowBase + wr * 128 + m * 16 + l4 * 4 + r;
                int col = colBase + wc * 64 + n * 16 + l15;
                if (OUT_BF16)
                    ((ushort*)Cv)[(size_t)row * N + col] = f2b(acc[m][n][r]);
                else
                    ((float*)Cv)[(size_t)row * N + col] = acc[m][n][r];
            }

    // ---- fused per-64-row-chunk EMA aggregates (2 chunks per wave) ----
    if (DO_AGG) {
        const int bidx = rowBase >> 12;
        const int chunkBase = ((rowBase & 4095) >> 6) + wr * 2;
        #pragma unroll
        for (int h = 0; h < 2; ++h) {
            #pragma unroll
            for (int n = 0; n < 4; ++n) {
                int col = colBase + wc * 64 + n * 16 + l15;
                float qe = qv[col];
                float q2 = qe * qe, q4 = q2 * q2, q8 = q4 * q4, q16 = q8 * q8;
                float P = 0.0f;
                #pragma unroll
                for (int m = 3; m >= 0; --m) {
                    f32x4 a = acc[h * 4 + m][n];
                    float pm = ((a[3] * qe + a[2]) * qe + a[1]) * qe + a[0];
                    P = P * q16 + pm;
                }
                float ql4 = (l4 & 1 ? q4 : 1.0f) * (l4 & 2 ? q8 : 1.0f);
                P *= ql4;
                P += __shfl_xor(P, 16, 64);
                P += __shfl_xor(P, 32, 64);
                if (l4 == 0)
                    aggp[(((bidx << 6) | (chunkBase + h)) << 10) + col] = P;
            }
        }
    }
}

// ------------------------------- GEMM 128x128 (m97 structure, for gemm2) --
template <int OUT_BF16>
__global__ __launch_bounds__(256) void gemm_bt(const ushort* __restrict__ A,
                                               const ushort* __restrict__ Bt,
                                               void* __restrict__ Cv,
                                               int M, int N, int K,
                                               int ncolShift) {
    __shared__ ushort smem[16384];
    const int tid  = threadIdx.x;
    const int lane = tid & 63;
    const int wid  = tid >> 6;
    const int wr   = wid >> 1, wc = wid & 1;
    const int l15  = lane & 15;
    const int l4   = lane >> 4;

    const int nwg   = gridDim.x;
    const int chunkw = nwg >> 3;
    const int flat  = (blockIdx.x & 7) * chunkw + (blockIdx.x >> 3);
    const int rowBase = (flat >> ncolShift) << 7;
    const int colBase = (flat & ((1 << ncolShift) - 1)) << 7;

    f32x4 acc[4][4] = {};

    const int nkb = K >> 6;
    for (int kb = 0; kb < nkb; ++kb) {
        #pragma unroll
        for (int r = 0; r < 4; ++r) {
            int c     = r * 256 + tid;
            int row   = c >> 3;
            int col16 = (c & 7) ^ (row & 7);
            const ushort* ga = A  + (size_t)(rowBase + row) * K + kb * 64 + col16 * 8;
            __builtin_amdgcn_global_load_lds(
                (const __attribute__((address_space(1))) void*)ga,
                (__attribute__((address_space(3))) void*)((char*)smem + c * 16),
                16, 0, 0);
            const ushort* gb = Bt + (size_t)(colBase + row) * K + kb * 64 + col16 * 8;
            __builtin_amdgcn_global_load_lds(
                (const __attribute__((address_space(1))) void*)gb,
                (__attribute__((address_space(3))) void*)((char*)smem + 16384 + c * 16),
                16, 0, 0);
        }
        __syncthreads();

        #pragma unroll
        for (int kk = 0; kk < 2; ++kk) {
            bf16x8 af[4], bfr[4];
            #pragma unroll
            for (int m = 0; m < 4; ++m) {
                int row   = wr * 64 + m * 16 + l15;
                int kbyte = kk * 64 + l4 * 16;
                int addr  = row * 128 + (kbyte ^ ((row & 7) << 4));
                af[m] = *(const bf16x8*)((const char*)smem + addr);
            }
            #pragma unroll
            for (int n = 0; n < 4; ++n) {
                int row   = wc * 64 + n * 16 + l15;
                int kbyte = kk * 64 + l4 * 16;
                int addr  = 16384 + row * 128 + (kbyte ^ ((row & 7) << 4));
                bfr[n] = *(const bf16x8*)((const char*)smem + addr);
            }
            #pragma unroll
            for (int m = 0; m < 4; ++m)
                #pragma unroll
                for (int n = 0; n < 4; ++n)
                    acc[m][n] = __builtin_amdgcn_mfma_f32_16x16x32_bf16(
                        af[m], bfr[n], acc[m][n], 0, 0, 0);
        }
        __syncthreads();
    }

    #pragma unroll
    for (int m = 0; m < 4; ++m)
        #pragma unroll
        for (int n = 0; n < 4; ++n)
            #pragma unroll
            for (int r = 0; r < 4; ++r) {
                int row = rowBase + wr * 64 + m * 16 + l4 * 4 + r;
                int col = colBase + wc * 64 + n * 16 + l15;
                if (OUT_BF16)
                    ((ushort*)Cv)[(size_t)row * N + col] = f2b(acc[m][n][r]);
                else
                    ((float*)Cv)[(size_t)row * N + col] = acc[m][n][r];
            }
}

// ---------------------------------------------------------------- scan ----
__global__ void scan_apply_kernel(ushort* __restrict__ u,
                                  const float* __restrict__ pv,
                                  const float* __restrict__ qv,
                                  const float* __restrict__ agg) {
    int t = blockIdx.x * blockDim.x + threadIdx.x;   // 131072
    int e0 = (t & 511) * 2;
    int c  = (t >> 9) & 63;
    int b  = t >> 15;
    float2 qe2 = *(const float2*)(qv + e0);
    float2 pe2 = *(const float2*)(pv + e0);
    float qe[2] = {qe2.x, qe2.y};
    float pe[2] = {pe2.x, pe2.y};
    float qL[2], S[2], w[2];
    #pragma unroll
    for (int k = 0; k < 2; ++k) {
        float x = qe[k];
        #pragma unroll
        for (int s = 0; s < 6; ++s) x *= x;    // q^64
        qL[k] = x; S[k] = 0.0f; w[k] = 1.0f;
    }
    for (int cp = c + 1; cp < NCHUNK; ++cp) {
        float2 a = *(const float2*)(agg + (((b << 6) | cp) << 10) + e0);
        S[0] += w[0] * a.x;  w[0] *= qL[0];
        S[1] += w[1] * a.y;  w[1] *= qL[1];
    }
    ushort* up = u + ((size_t)(b * LSEQ + c * CHUNK) << 10) + e0;
    #pragma unroll 4
    for (int j = CHUNK - 1; j >= 0; --j) {
        ushort2 uv = *(ushort2*)(up + (size_t)j * EDIM);
        S[0] = b2f(uv.x) + qe[0] * S[0];
        S[1] = b2f(uv.y) + qe[1] * S[1];
        ushort2 ov;
        ov.x = f2b(pe[0] * S[0]);
        ov.y = f2b(pe[1] * S[1]);
        *(ushort2*)(up + (size_t)j * EDIM) = ov;
    }
}

// -------------------------------------------------------------- launch ----
extern "C" void kernel_launch(void* const* d_in, const int* in_sizes, int n_in,
                              void* d_out, int out_size, void* d_ws, size_t ws_size,
                              hipStream_t stream) {
    const float* emb  = (const float*)d_in[0];
    const float* la   = (const float*)d_in[1];
    const float* ld   = (const float*)d_in[2];
    const float* beta = (const float*)d_in[3];
    const float* eta  = (const float*)d_in[4];

    char* ws = (char*)d_ws;
    ushort* a16   = (ushort*)(ws);                    // 16 MB  emb bf16
    ushort* betaT = (ushort*)(ws + 16777216);         // 1 MB
    ushort* etaT  = (ushort*)(ws + 17825792);         // 1 MB
    ushort* u     = (ushort*)(ws + 18874368);         // 32 MB  u (in-place out)
    float*  p     = (float*) (ws + 52428800);         // 4 KB
    float*  q     = (float*) (ws + 52432896);         // 4 KB
    float*  agg   = (float*) (ws + 52436992);         // 1 MB [4][64][1024]

    // allow 128 KB dynamic LDS for gemm256 (idempotent; ignore errors)
    (void)hipFuncSetAttribute((const void*)gemm256<512, 2, 1, 1>,
                              hipFuncAttributeMaxDynamicSharedMemorySize, 131072);

    prep_cvt_kernel<<<dim3(10240), dim3(256), 0, stream>>>(
        emb, a16, beta, eta, la, ld, betaT, etaT, p, q);

    // u[16384,1024] = emb_bf16 @ betaT^T   (256x256 8-phase, fused agg)
    gemm256<512, 2, 1, 1><<<dim3(256), dim3(512), 131072, stream>>>(
        a16, betaT, (void*)u, q, agg, EDIM);

    scan_apply_kernel<<<dim3(512), dim3(256), 0, stream>>>(u, p, q, agg);

    // y[16384,512] = out_bf16 @ etaT^T     (128x128 structure)
    gemm_bt<0><<<dim3((MROWS / 128) * (OUTD / 128)), dim3(256), 0, stream>>>(
        u, etaT, d_out, MROWS, OUTD, EDIM, 2);
}